// Round 7
// baseline (125.800 us; speedup 1.0000x reference)
//
#include <hip/hip_runtime.h>
#include <math.h>

#define NUM_CLASSES 80
#define OBJ_BLOCKS 1536                 // 3 scales x 16 batch x 32 targets
#define NEG_BLOCKS 788                  // ceil(100800 float4 / 128)
#define TOTAL_BLOCKS (OBJ_BLOCKS + NEG_BLOCKS)
#define NEG_BASE (OBJ_BLOCKS * 8)       // float offset of neg partials in ws

// ---- math helpers (match jax.nn.log_sigmoid / sigmoid in f32) ----
__device__ __forceinline__ float softplusf_(float x) {
    return x > 0.f ? x + log1pf(expf(-x)) : log1pf(expf(x));
}
__device__ __forceinline__ float sigmoidf_(float x) {
    return 1.f / (1.f + expf(-x));
}
// focal_bce(x, t=0) = softplus(x) * sigmoid(x)^2
__device__ __forceinline__ float focal0(float x) {
    float s = sigmoidf_(x);
    return softplusf_(x) * s * s;
}
// focal_bce(x, t=1) = softplus(-x) * sigmoid(-x)^2
__device__ __forceinline__ float focal1(float x) {
    float s = sigmoidf_(-x);
    return softplusf_(-x) * s * s;
}

// device-coherent ws accessors (bypass per-XCD L2 — agent scope)
__device__ __forceinline__ void st_ws(float* p, float v) {
    __hip_atomic_store(p, v, __ATOMIC_RELAXED, __HIP_MEMORY_SCOPE_AGENT);
}
__device__ __forceinline__ float ld_ws(const float* p) {
    return __hip_atomic_load(p, __ATOMIC_RELAXED, __HIP_MEMORY_SCOPE_AGENT);
}

// completion counter: zero-init at module load; last block resets it to 0
// every call -> no state carried across calls, fully deterministic.
__device__ unsigned g_done = 0;

// ws layout (floats):
//   [bid*8 .. +7]        obj partial slot: [0]=xy [1]=wh [2]=cls [3]=pos
//                        [4]=neg_corr [5]=count [6,7]=0   (bid < 1536)
//   [NEG_BASE + q]       neg partial of neg-block q       (q < 788)
// Every slot is written unconditionally every call -> poison-safe, no memset.

__global__ __launch_bounds__(128)
void fused_kernel(const float* __restrict__ p0,
                  const float* __restrict__ p1,
                  const float* __restrict__ p2,
                  const float* __restrict__ tgt,
                  float* __restrict__ ws,
                  float* __restrict__ out) {
    __shared__ int   s_cell[32];
    __shared__ int   s_cls[32];
    __shared__ float s_sum[5];
    __shared__ float s_ns[2];
    __shared__ float s_red[2][6];
    __shared__ float s_nred[2][3];
    __shared__ bool  amLast;

    const int bid = blockIdx.x;
    const int f   = threadIdx.x;          // 128 threads = 2 waves

    if (bid < OBJ_BLOCKS) {
        // ================= object-cell path =================
        const int s = bid >> 9;            // /512
        const int r = bid & 511;
        const int b = r >> 5;              // /32
        const int t = r & 31;
        const int H  = (s == 0) ? 80 : (s == 1 ? 40 : 20);
        const int W  = H;
        const int HW = H * W;

        // ANCHORS[s] / 640 in registers (no runtime-indexed arrays)
        float aw0, aw1, aw2, ah0, ah1, ah2;
        if (s == 0) { aw0=10.f/640.f; aw1=16.f/640.f; aw2=33.f/640.f;
                      ah0=13.f/640.f; ah1=30.f/640.f; ah2=23.f/640.f; }
        else if (s == 1) { aw0=30.f/640.f; aw1=62.f/640.f; aw2=59.f/640.f;
                           ah0=61.f/640.f; ah1=45.f/640.f; ah2=119.f/640.f; }
        else { aw0=116.f/640.f; aw1=156.f/640.f; aw2=373.f/640.f;
               ah0=90.f/640.f;  ah1=198.f/640.f; ah2=326.f/640.f; }

        if (f < 5) s_sum[f] = 0.f;

        if (f < 32) {
            const float* tg = tgt + (size_t)(b * 32 + f) * 5;
            const float w = tg[3], h = tg[4];
            int cell = -1;
            if (w > 0.f && h > 0.f) {
                // argmax IoU over 3 anchors, first-max on ties (strict >)
                float best = -1.f; int ba = 0;
                float inter = fminf(w, aw0) * fminf(h, ah0);
                float iou = inter / (w * h + aw0 * ah0 - inter + 1e-6f);
                if (iou > best) { best = iou; ba = 0; }
                inter = fminf(w, aw1) * fminf(h, ah1);
                iou = inter / (w * h + aw1 * ah1 - inter + 1e-6f);
                if (iou > best) { best = iou; ba = 1; }
                inter = fminf(w, aw2) * fminf(h, ah2);
                iou = inter / (w * h + aw2 * ah2 - inter + 1e-6f);
                if (iou > best) { best = iou; ba = 2; }
                const float xw = tg[1] * (float)W, yh = tg[2] * (float)H;
                int gi = (int)xw; gi = min(max(gi, 0), W - 1); // trunc == astype(i32)
                int gj = (int)yh; gj = min(max(gj, 0), H - 1);
                cell = (ba * H + gj) * W + gi;                 // b uniform in block
            }
            s_cell[f] = cell;
            s_cls[f]  = (int)tg[0];
        }
        __syncthreads();

        const int mycell = s_cell[t];
        bool winner = (mycell >= 0);
        if (winner) {
            // numpy scatter = last-write-wins in t order within the batch
            #pragma unroll 1
            for (int t2 = t + 1; t2 < 32; ++t2)
                if (s_cell[t2] == mycell) { winner = false; break; }
        }
        // `winner` is block-uniform (depends only on bid)

        if (winner) {
            // class UNION over all targets hitting this cell
            unsigned um0 = 0, um1 = 0, um2 = 0;
            #pragma unroll 1
            for (int t2 = 0; t2 < 32; ++t2) {
                if (s_cell[t2] == mycell) {
                    const int c = s_cls[t2];
                    if (c < 32)      um0 |= 1u << c;
                    else if (c < 64) um1 |= 1u << (c - 32);
                    else             um2 |= 1u << (c - 64);
                }
            }

            // geometry of target t (uniform; recomputed by all lanes)
            const float* tg = tgt + (size_t)(b * 32 + t) * 5;
            const float w = tg[3], h = tg[4];
            float best = -1.f; int ba = 0;
            {
                float inter = fminf(w, aw0) * fminf(h, ah0);
                float iou = inter / (w * h + aw0 * ah0 - inter + 1e-6f);
                if (iou > best) { best = iou; ba = 0; }
                inter = fminf(w, aw1) * fminf(h, ah1);
                iou = inter / (w * h + aw1 * ah1 - inter + 1e-6f);
                if (iou > best) { best = iou; ba = 1; }
                inter = fminf(w, aw2) * fminf(h, ah2);
                iou = inter / (w * h + aw2 * ah2 - inter + 1e-6f);
                if (iou > best) { best = iou; ba = 2; }
            }
            const float aw = (ba == 0) ? aw0 : (ba == 1 ? aw1 : aw2);
            const float ah = (ba == 0) ? ah0 : (ba == 1 ? ah1 : ah2);
            const float xw = tg[1] * (float)W, yh = tg[2] * (float)H;
            int gi = (int)xw; gi = min(max(gi, 0), W - 1);
            int gj = (int)yh; gj = min(max(gj, 0), H - 1);

            if (f < 85) {
                const float* P = (s == 0) ? p0 : (s == 1 ? p1 : p2);
                const float val = P[(size_t)(b * 255 + ba * 85 + f) * HW
                                    + (size_t)gj * W + gi];
                float contrib; int cat;
                if (f == 0) {
                    const float d = sigmoidf_(val) - (xw - (float)gi);
                    contrib = d * d; cat = 0;
                } else if (f == 1) {
                    const float d = sigmoidf_(val) - (yh - (float)gj);
                    contrib = d * d; cat = 0;
                } else if (f == 2) {
                    const float e = val - logf(w / aw + 1e-6f);
                    contrib = e * e; cat = 1;
                } else if (f == 3) {
                    const float e = val - logf(h / ah + 1e-6f);
                    contrib = e * e; cat = 1;
                } else if (f == 4) {
                    contrib = focal1(val); cat = 3;
                    atomicAdd(&s_sum[4], -focal0(val)); // correction to all-cell neg
                } else {
                    const int c = f - 5;
                    const bool ts = (c < 32) ? ((um0 >> c) & 1)
                                  : (c < 64) ? ((um1 >> (c - 32)) & 1)
                                             : ((um2 >> (c - 64)) & 1);
                    contrib = ts ? focal1(val) : focal0(val); cat = 2;
                }
                atomicAdd(&s_sum[cat], contrib);
            }
        }
        __syncthreads();
        float* slot = ws + (size_t)bid * 8;
        if (f < 8) {
            float v = 0.f;
            if (winner) v = (f < 5) ? s_sum[f] : (f == 5 ? 1.f : 0.f);
            st_ws(slot + f, v);
        }
    } else {
        // ================= all-cell negative path =================
        // float4 counts: scale0 76800 (blocks 0..599), scale1 19200
        // (600..749), scale2 4800 (750..787, last block half-active).
        const int q   = bid - OBJ_BLOCKS;
        const int idx = q * 128 + f;
        float sum = 0.f;
        if (idx < 100800) {
            int q4, plane4;
            const float* P;
            if (idx < 76800)      { P = p0; q4 = idx;          plane4 = 1600; }
            else if (idx < 96000) { P = p1; q4 = idx - 76800;  plane4 = 400;  }
            else                  { P = p2; q4 = idx - 96000;  plane4 = 100;  }
            const int plane = q4 / plane4;
            const int r4 = q4 - plane * plane4;
            const int b = plane / 3;
            const int a = plane - b * 3;
            const int HW = plane4 * 4;
            const float4 v = *reinterpret_cast<const float4*>(
                P + (size_t)(b * 255 + a * 85 + 4) * HW + (size_t)r4 * 4);
            sum = focal0(v.x) + focal0(v.y) + focal0(v.z) + focal0(v.w);
        }
        #pragma unroll
        for (int off = 32; off; off >>= 1) sum += __shfl_down(sum, off, 64);
        if ((f & 63) == 0) s_ns[f >> 6] = sum;
        __syncthreads();
        if (f == 0) st_ws(ws + NEG_BASE + q, s_ns[0] + s_ns[1]);
    }

    // ============ completion protocol (last block finalizes) ============
    __threadfence();                       // publish this block's ws stores
    __syncthreads();                       // drains vmcnt before barrier
    if (f == 0) {
        const unsigned old = __hip_atomic_fetch_add(
            &g_done, 1u, __ATOMIC_ACQ_REL, __HIP_MEMORY_SCOPE_AGENT);
        amLast = (old == TOTAL_BLOCKS - 1);
    }
    __syncthreads();
    if (!amLast) return;

    if (f == 0)  // reset for the next call (no one reads it until then)
        __hip_atomic_store(&g_done, 0u, __ATOMIC_RELAXED,
                           __HIP_MEMORY_SCOPE_AGENT);
    __threadfence();                       // acquire side: invalidate caches

    // ---- neg partials -> per-scale sums ----
    float n0 = 0.f, n1 = 0.f, n2 = 0.f;
    for (int q = f; q < NEG_BLOCKS; q += 128) {
        const float v = ld_ws(ws + NEG_BASE + q);
        if (q < 600)      n0 += v;
        else if (q < 750) n1 += v;
        else              n2 += v;
    }
    #pragma unroll
    for (int off = 32; off; off >>= 1) {
        n0 += __shfl_down(n0, off, 64);
        n1 += __shfl_down(n1, off, 64);
        n2 += __shfl_down(n2, off, 64);
    }
    if ((f & 63) == 0) {
        const int wv = f >> 6;
        s_nred[wv][0] = n0; s_nred[wv][1] = n1; s_nred[wv][2] = n2;
    }
    __syncthreads();

    // ---- obj slots -> per-scale sums + final scalar ----
    float total = 0.f;                      // live in thread 0
    #pragma unroll 1
    for (int s = 0; s < 3; ++s) {
        float v0 = 0.f, v1 = 0.f, v2 = 0.f, v3 = 0.f, v4 = 0.f, v5 = 0.f;
        for (int i = f; i < 512; i += 128) {     // 4 slots per thread
            const float* sl = ws + (size_t)(s * 512 + i) * 8;
            v0 += ld_ws(sl + 0); v1 += ld_ws(sl + 1); v2 += ld_ws(sl + 2);
            v3 += ld_ws(sl + 3); v4 += ld_ws(sl + 4); v5 += ld_ws(sl + 5);
        }
        #pragma unroll
        for (int off = 32; off; off >>= 1) {
            v0 += __shfl_down(v0, off, 64); v1 += __shfl_down(v1, off, 64);
            v2 += __shfl_down(v2, off, 64); v3 += __shfl_down(v3, off, 64);
            v4 += __shfl_down(v4, off, 64); v5 += __shfl_down(v5, off, 64);
        }
        if ((f & 63) == 0) {
            const int wv = f >> 6;
            s_red[wv][0] = v0; s_red[wv][1] = v1; s_red[wv][2] = v2;
            s_red[wv][3] = v3; s_red[wv][4] = v4; s_red[wv][5] = v5;
        }
        __syncthreads();
        if (f == 0) {
            const float sxy  = s_red[0][0] + s_red[1][0];
            const float swh  = s_red[0][1] + s_red[1][1];
            const float scls = s_red[0][2] + s_red[1][2];
            const float spos = s_red[0][3] + s_red[1][3];
            const float scor = s_red[0][4] + s_red[1][4];
            const float nobj = s_red[0][5] + s_red[1][5];
            const float negs = s_nred[0][s] + s_nred[1][s];
            const float Ns = (s == 0) ? (float)(16 * 3 * 6400)
                           : (s == 1) ? (float)(16 * 3 * 1600)
                                      : (float)(16 * 3 * 400);
            const float n_noobj = Ns - nobj;
            const float lxywh = (sxy + swh) / fmaxf(2.f * nobj, 1.f);
            const float lcls  = scls / fmaxf(nobj * (float)NUM_CLASSES, 1.f);
            const float lpos  = spos / fmaxf(nobj, 1.f);
            const float lneg  = (negs + scor) / fmaxf(n_noobj, 1.f);
            const float has   = (nobj > 0.f) ? 1.f : 0.f;
            total += 5.f * lxywh * has + lpos * has + 0.5f * lneg + lcls * has;
        }
        __syncthreads();
    }
    if (f == 0) out[0] = total / 3.f;
}

extern "C" void kernel_launch(void* const* d_in, const int* in_sizes, int n_in,
                              void* d_out, int out_size, void* d_ws, size_t ws_size,
                              hipStream_t stream) {
    const float* p0  = (const float*)d_in[0];
    const float* p1  = (const float*)d_in[1];
    const float* p2  = (const float*)d_in[2];
    const float* tgt = (const float*)d_in[3];
    float* ws  = (float*)d_ws;   // needs (1536*8 + 788) floats ~= 52 KB
    float* out = (float*)d_out;

    fused_kernel<<<TOTAL_BLOCKS, 128, 0, stream>>>(p0, p1, p2, tgt, ws, out);
}

// Round 8
// 27.857 us; speedup vs baseline: 4.5159x; 4.5159x over previous
//
#include <hip/hip_runtime.h>
#include <math.h>

#define NUM_CLASSES 80
#define OBJ_BLOCKS 1536                 // 3 scales x 16 batch x 32 targets
#define NEG_BLOCKS 788                  // ceil(100800 float4 / 128)
#define TOTAL_BLOCKS (OBJ_BLOCKS + NEG_BLOCKS)
#define NEG_BASE (OBJ_BLOCKS * 8)       // float offset of neg partials in ws

// ---- math helpers (match jax.nn.log_sigmoid / sigmoid in f32) ----
__device__ __forceinline__ float softplusf_(float x) {
    return x > 0.f ? x + log1pf(expf(-x)) : log1pf(expf(x));
}
__device__ __forceinline__ float sigmoidf_(float x) {
    return 1.f / (1.f + expf(-x));
}
// focal_bce(x, t=0) = softplus(x) * sigmoid(x)^2
__device__ __forceinline__ float focal0(float x) {
    float s = sigmoidf_(x);
    return softplusf_(x) * s * s;
}
// focal_bce(x, t=1) = softplus(-x) * sigmoid(-x)^2
__device__ __forceinline__ float focal1(float x) {
    float s = sigmoidf_(-x);
    return softplusf_(-x) * s * s;
}

// ws layout (floats):
//   [bid*8 .. +7]   obj partial slot: [0]=xy [1]=wh [2]=cls [3]=pos
//                   [4]=neg_corr [5]=count [6,7]=0     (bid < 1536)
//   [NEG_BASE + q]  neg partial of neg-block q          (q < 788)
// Every slot is written unconditionally every call -> poison-safe, no memset.
// Coherence between the two dispatches comes from the kernel boundary —
// no fences/atomic counters (R7's single-cacheline device-scope fetch_add
// serialized at ~73 ns/block = 170 us; never again).

__global__ __launch_bounds__(128)
void work_kernel(const float* __restrict__ p0,
                 const float* __restrict__ p1,
                 const float* __restrict__ p2,
                 const float* __restrict__ tgt,
                 float* __restrict__ ws) {
    __shared__ int   s_cell[32];
    __shared__ int   s_cls[32];
    __shared__ float s_sum[5];
    __shared__ float s_ns[2];

    const int bid = blockIdx.x;
    const int f   = threadIdx.x;          // 128 threads = 2 waves

    if (bid < OBJ_BLOCKS) {
        // ================= object-cell path =================
        const int s = bid >> 9;            // /512
        const int r = bid & 511;
        const int b = r >> 5;              // /32
        const int t = r & 31;
        const int H  = (s == 0) ? 80 : (s == 1 ? 40 : 20);
        const int W  = H;
        const int HW = H * W;

        // ANCHORS[s] / 640 in registers (no runtime-indexed arrays)
        float aw0, aw1, aw2, ah0, ah1, ah2;
        if (s == 0) { aw0=10.f/640.f; aw1=16.f/640.f; aw2=33.f/640.f;
                      ah0=13.f/640.f; ah1=30.f/640.f; ah2=23.f/640.f; }
        else if (s == 1) { aw0=30.f/640.f; aw1=62.f/640.f; aw2=59.f/640.f;
                           ah0=61.f/640.f; ah1=45.f/640.f; ah2=119.f/640.f; }
        else { aw0=116.f/640.f; aw1=156.f/640.f; aw2=373.f/640.f;
               ah0=90.f/640.f;  ah1=198.f/640.f; ah2=326.f/640.f; }

        if (f < 5) s_sum[f] = 0.f;

        if (f < 32) {
            const float* tg = tgt + (size_t)(b * 32 + f) * 5;
            const float w = tg[3], h = tg[4];
            int cell = -1;
            if (w > 0.f && h > 0.f) {
                // argmax IoU over 3 anchors, first-max on ties (strict >)
                float best = -1.f; int ba = 0;
                float inter = fminf(w, aw0) * fminf(h, ah0);
                float iou = inter / (w * h + aw0 * ah0 - inter + 1e-6f);
                if (iou > best) { best = iou; ba = 0; }
                inter = fminf(w, aw1) * fminf(h, ah1);
                iou = inter / (w * h + aw1 * ah1 - inter + 1e-6f);
                if (iou > best) { best = iou; ba = 1; }
                inter = fminf(w, aw2) * fminf(h, ah2);
                iou = inter / (w * h + aw2 * ah2 - inter + 1e-6f);
                if (iou > best) { best = iou; ba = 2; }
                const float xw = tg[1] * (float)W, yh = tg[2] * (float)H;
                int gi = (int)xw; gi = min(max(gi, 0), W - 1); // trunc == astype(i32)
                int gj = (int)yh; gj = min(max(gj, 0), H - 1);
                cell = (ba * H + gj) * W + gi;                 // b uniform in block
            }
            s_cell[f] = cell;
            s_cls[f]  = (int)tg[0];
        }
        __syncthreads();

        const int mycell = s_cell[t];
        bool winner = (mycell >= 0);
        if (winner) {
            // numpy scatter = last-write-wins in t order within the batch
            #pragma unroll 1
            for (int t2 = t + 1; t2 < 32; ++t2)
                if (s_cell[t2] == mycell) { winner = false; break; }
        }
        // `winner` is block-uniform (depends only on bid)

        if (winner) {
            // class UNION over all targets hitting this cell
            unsigned um0 = 0, um1 = 0, um2 = 0;
            #pragma unroll 1
            for (int t2 = 0; t2 < 32; ++t2) {
                if (s_cell[t2] == mycell) {
                    const int c = s_cls[t2];
                    if (c < 32)      um0 |= 1u << c;
                    else if (c < 64) um1 |= 1u << (c - 32);
                    else             um2 |= 1u << (c - 64);
                }
            }

            // geometry of target t (uniform; recomputed by all lanes)
            const float* tg = tgt + (size_t)(b * 32 + t) * 5;
            const float w = tg[3], h = tg[4];
            float best = -1.f; int ba = 0;
            {
                float inter = fminf(w, aw0) * fminf(h, ah0);
                float iou = inter / (w * h + aw0 * ah0 - inter + 1e-6f);
                if (iou > best) { best = iou; ba = 0; }
                inter = fminf(w, aw1) * fminf(h, ah1);
                iou = inter / (w * h + aw1 * ah1 - inter + 1e-6f);
                if (iou > best) { best = iou; ba = 1; }
                inter = fminf(w, aw2) * fminf(h, ah2);
                iou = inter / (w * h + aw2 * ah2 - inter + 1e-6f);
                if (iou > best) { best = iou; ba = 2; }
            }
            const float aw = (ba == 0) ? aw0 : (ba == 1 ? aw1 : aw2);
            const float ah = (ba == 0) ? ah0 : (ba == 1 ? ah1 : ah2);
            const float xw = tg[1] * (float)W, yh = tg[2] * (float)H;
            int gi = (int)xw; gi = min(max(gi, 0), W - 1);
            int gj = (int)yh; gj = min(max(gj, 0), H - 1);

            if (f < 85) {
                const float* P = (s == 0) ? p0 : (s == 1 ? p1 : p2);
                const float val = P[(size_t)(b * 255 + ba * 85 + f) * HW
                                    + (size_t)gj * W + gi];
                float contrib; int cat;
                if (f == 0) {
                    const float d = sigmoidf_(val) - (xw - (float)gi);
                    contrib = d * d; cat = 0;
                } else if (f == 1) {
                    const float d = sigmoidf_(val) - (yh - (float)gj);
                    contrib = d * d; cat = 0;
                } else if (f == 2) {
                    const float e = val - logf(w / aw + 1e-6f);
                    contrib = e * e; cat = 1;
                } else if (f == 3) {
                    const float e = val - logf(h / ah + 1e-6f);
                    contrib = e * e; cat = 1;
                } else if (f == 4) {
                    contrib = focal1(val); cat = 3;
                    atomicAdd(&s_sum[4], -focal0(val)); // correction to all-cell neg
                } else {
                    const int c = f - 5;
                    const bool ts = (c < 32) ? ((um0 >> c) & 1)
                                  : (c < 64) ? ((um1 >> (c - 32)) & 1)
                                             : ((um2 >> (c - 64)) & 1);
                    contrib = ts ? focal1(val) : focal0(val); cat = 2;
                }
                atomicAdd(&s_sum[cat], contrib);
            }
        }
        __syncthreads();
        float* slot = ws + (size_t)bid * 8;
        if (f < 8) {
            float v = 0.f;
            if (winner) v = (f < 5) ? s_sum[f] : (f == 5 ? 1.f : 0.f);
            slot[f] = v;
        }
    } else {
        // ================= all-cell negative path =================
        // float4 counts: scale0 76800 (q 0..599), scale1 19200 (600..749),
        // scale2 4800 (750..787, last block half-active).
        const int q   = bid - OBJ_BLOCKS;
        const int idx = q * 128 + f;
        float sum = 0.f;
        if (idx < 100800) {
            int q4, plane4;
            const float* P;
            if (idx < 76800)      { P = p0; q4 = idx;          plane4 = 1600; }
            else if (idx < 96000) { P = p1; q4 = idx - 76800;  plane4 = 400;  }
            else                  { P = p2; q4 = idx - 96000;  plane4 = 100;  }
            const int plane = q4 / plane4;
            const int r4 = q4 - plane * plane4;
            const int b = plane / 3;
            const int a = plane - b * 3;
            const int HW = plane4 * 4;
            const float4 v = *reinterpret_cast<const float4*>(
                P + (size_t)(b * 255 + a * 85 + 4) * HW + (size_t)r4 * 4);
            sum = focal0(v.x) + focal0(v.y) + focal0(v.z) + focal0(v.w);
        }
        #pragma unroll
        for (int off = 32; off; off >>= 1) sum += __shfl_down(sum, off, 64);
        if ((f & 63) == 0) s_ns[f >> 6] = sum;
        __syncthreads();
        if (f == 0) ws[NEG_BASE + q] = s_ns[0] + s_ns[1];
    }
}

// ---- Kernel F: reduce all partials + finalize scalar ----
__global__ __launch_bounds__(512)
void finalize_kernel(const float* __restrict__ ws,
                     float* __restrict__ out) {
    __shared__ float s_red[8][6];
    __shared__ float s_nred[8][3];
    __shared__ float s_total;
    const int tid  = threadIdx.x;            // 512 threads
    const int lane = tid & 63;
    const int wid  = tid >> 6;
    if (tid == 0) s_total = 0.f;

    // neg partials -> per-scale sums
    float n0 = 0.f, n1 = 0.f, n2 = 0.f;
    for (int q = tid; q < NEG_BLOCKS; q += 512) {
        const float v = ws[NEG_BASE + q];
        if (q < 600)      n0 += v;
        else if (q < 750) n1 += v;
        else              n2 += v;
    }
    #pragma unroll
    for (int off = 32; off; off >>= 1) {
        n0 += __shfl_down(n0, off, 64);
        n1 += __shfl_down(n1, off, 64);
        n2 += __shfl_down(n2, off, 64);
    }
    if (lane == 0) { s_nred[wid][0] = n0; s_nred[wid][1] = n1; s_nred[wid][2] = n2; }

    // obj slots -> per-scale sums + final scalar
    #pragma unroll 1
    for (int s = 0; s < 3; ++s) {
        const float* slot = ws + (size_t)(s * 512 + tid) * 8;
        float v[6];
        #pragma unroll
        for (int k = 0; k < 6; ++k) v[k] = slot[k];
        #pragma unroll
        for (int off = 32; off; off >>= 1)
            #pragma unroll
            for (int k = 0; k < 6; ++k) v[k] += __shfl_down(v[k], off, 64);
        if (lane == 0) {
            #pragma unroll
            for (int k = 0; k < 6; ++k) s_red[wid][k] = v[k];
        }
        __syncthreads();
        if (tid == 0) {
            float sum[6] = {0.f, 0.f, 0.f, 0.f, 0.f, 0.f};
            float negs = 0.f;
            for (int wv = 0; wv < 8; ++wv) {
                #pragma unroll
                for (int k = 0; k < 6; ++k) sum[k] += s_red[wv][k];
                negs += s_nred[wv][s];
            }
            const float Ns = (s == 0) ? (float)(16 * 3 * 6400)
                           : (s == 1) ? (float)(16 * 3 * 1600)
                                      : (float)(16 * 3 * 400);
            const float n_obj   = sum[5];
            const float n_noobj = Ns - n_obj;
            const float lxywh = (sum[0] + sum[1]) / fmaxf(2.f * n_obj, 1.f);
            const float lcls  = sum[2] / fmaxf(n_obj * (float)NUM_CLASSES, 1.f);
            const float lpos  = sum[3] / fmaxf(n_obj, 1.f);
            const float lneg  = (negs + sum[4]) / fmaxf(n_noobj, 1.f);
            const float has   = (n_obj > 0.f) ? 1.f : 0.f;
            s_total += 5.f * lxywh * has + lpos * has + 0.5f * lneg + lcls * has;
        }
        __syncthreads();
    }
    if (tid == 0) out[0] = s_total / 3.f;
}

extern "C" void kernel_launch(void* const* d_in, const int* in_sizes, int n_in,
                              void* d_out, int out_size, void* d_ws, size_t ws_size,
                              hipStream_t stream) {
    const float* p0  = (const float*)d_in[0];
    const float* p1  = (const float*)d_in[1];
    const float* p2  = (const float*)d_in[2];
    const float* tgt = (const float*)d_in[3];
    float* ws  = (float*)d_ws;   // needs (1536*8 + 788) floats ~= 52 KB
    float* out = (float*)d_out;

    work_kernel<<<TOTAL_BLOCKS, 128, 0, stream>>>(p0, p1, p2, tgt, ws);
    finalize_kernel<<<1, 512, 0, stream>>>(ws, out);
}